// Round 13
// baseline (237.632 us; speedup 1.0000x reference)
//
#include <hip/hip_runtime.h>

typedef __attribute__((ext_vector_type(8))) short short8;
typedef __attribute__((ext_vector_type(4))) float f32x4;
typedef __attribute__((ext_vector_type(16))) float f32x16;
typedef __attribute__((ext_vector_type(4))) unsigned short u16x4;
typedef __attribute__((ext_vector_type(4))) float float4v;

#define AS1 __attribute__((address_space(1)))
#define AS3 __attribute__((address_space(3)))

#define T_SEQ 2048
#define C_EMB 1024
#define NHEAD 16
#define NB    4
#define SCL_Q 0.18033688f   // 0.125 * log2(e)

__device__ __forceinline__ unsigned short f2bf(float f) {
    union { float f; unsigned u; } cv; cv.f = f;
    unsigned u = cv.u;
    unsigned r = (u + 0x7FFFu + ((u >> 16) & 1u)) >> 16;
    return (unsigned short)r;
}

__device__ __forceinline__ void async_load16(const void* g, void* l) {
    __builtin_amdgcn_global_load_lds((const AS1 unsigned*)g, (AS3 unsigned*)l, 16, 0, 0);
}

// permlane32_swap builtin: r[0] = {a.lo-lanes, b.lo-lanes}, r[1] = {a.hi, b.hi}
__device__ __forceinline__ void plswap_u(unsigned &a, unsigned &b) {
    auto r = __builtin_amdgcn_permlane32_swap(a, b, false, false);
    a = r[0]; b = r[1];
}
__device__ __forceinline__ float plswap_max(float t) {
    union { float f; unsigned u; } c; c.f = t;
    auto r = __builtin_amdgcn_permlane32_swap(c.u, c.u, false, false);
    union { unsigned u; float f; } x0, x1; x0.u = r[0]; x1.u = r[1];
    return fmaxf(x0.f, x1.f);
}
__device__ __forceinline__ float plswap_sum(float t) {
    union { float f; unsigned u; } c; c.f = t;
    auto r = __builtin_amdgcn_permlane32_swap(c.u, c.u, false, false);
    union { unsigned u; float f; } x0, x1; x0.u = r[0]; x1.u = r[1];
    return x0.f + x1.f;
}

// ---------------- fused f32 -> bf16 convert (x + 4 weights, one launch) ----------------
__global__ void cvt_all(const float* __restrict__ x,
                        const float* __restrict__ wq, const float* __restrict__ wk,
                        const float* __restrict__ wv, const float* __restrict__ wp,
                        unsigned short* __restrict__ xb,
                        unsigned short* __restrict__ wqkv,
                        unsigned short* __restrict__ wpb) {
    const int blk = blockIdx.x;
    const float* src; unsigned short* dst; int idx;
    if (blk < 8192) {                       // x: 8M elems = 2M float4 = 8192 blocks
        src = x; dst = xb; idx = blk * 256 + threadIdx.x;
    } else {                                 // weights: 1024 blocks each
        int wsel = (blk - 8192) >> 10;
        idx = ((blk - 8192) & 1023) * 256 + threadIdx.x;
        src = (wsel == 0) ? wq : (wsel == 1) ? wk : (wsel == 2) ? wv : wp;
        dst = (wsel == 3) ? wpb : wqkv + (size_t)wsel * 1048576;
    }
    float4v v = ((const float4v*)src)[idx];
    u16x4 o;
    o[0] = f2bf(v[0]); o[1] = f2bf(v[1]); o[2] = f2bf(v[2]); o[3] = f2bf(v[3]);
    ((u16x4*)dst)[idx] = o;
}

// ---------------- fused QKV GEMM: [8192,1024] x [3072,1024]^T ----------------
__global__ void gemm_qkv(const unsigned short* __restrict__ A,
                         const unsigned short* __restrict__ W,
                         const float* __restrict__ bq,
                         const float* __restrict__ bk,
                         const float* __restrict__ bv,
                         unsigned short* __restrict__ Qo,
                         unsigned short* __restrict__ Ko,
                         unsigned short* __restrict__ Vt) {
    __shared__ __align__(16) unsigned short As[128 * 32];
    __shared__ __align__(16) unsigned short Bs[128 * 32];
    const int tid  = threadIdx.x;
    const int wid  = tid >> 6;
    const int lane = tid & 63;
    const int lg = lane >> 4, lr = lane & 15;
    const int wr = wid >> 1, wc = wid & 1;
    const int n0 = blockIdx.x * 128;
    const int m0 = blockIdx.y * 128;
    const int K = 1024;

    f32x4 acc[4][4] = {};

    for (int kt = 0; kt < K; kt += 32) {
        #pragma unroll
        for (int r = 0; r < 2; ++r) {
            int cb = r * 4 + wid;
            int chunk = cb * 64 + lane;
            int row = chunk >> 2;
            int col = (chunk & 3) * 8;
            async_load16(&A[(size_t)(m0 + row) * K + kt + col], (char*)As + cb * 1024);
            async_load16(&W[(size_t)(n0 + row) * K + kt + col], (char*)Bs + cb * 1024);
        }
        __syncthreads();
        short8 af[4], bfr[4];
        #pragma unroll
        for (int m = 0; m < 4; ++m)
            af[m] = *(const short8*)&As[(wr * 64 + m * 16 + lr) * 32 + lg * 8];
        #pragma unroll
        for (int n = 0; n < 4; ++n)
            bfr[n] = *(const short8*)&Bs[(wc * 64 + n * 16 + lr) * 32 + lg * 8];
        #pragma unroll
        for (int m = 0; m < 4; ++m)
            #pragma unroll
            for (int n = 0; n < 4; ++n)
                acc[m][n] = __builtin_amdgcn_mfma_f32_16x16x32_bf16(af[m], bfr[n], acc[m][n], 0, 0, 0);
        __syncthreads();
    }

    const int sel = n0 >> 10;                       // 0=Q 1=K 2=V (block-uniform)
    const int nl0 = n0 & 1023;
    const float* bias = (sel == 0) ? bq : (sel == 1) ? bk : bv;
    const float scale = (sel == 0) ? SCL_Q : 1.0f;

    #pragma unroll
    for (int n = 0; n < 4; ++n) {
        int cc = nl0 + wc * 64 + n * 16 + lr;
        float bvv = bias[cc];
        #pragma unroll
        for (int m = 0; m < 4; ++m) {
            int rr0 = m0 + wr * 64 + m * 16 + lg * 4;
            u16x4 pk;
            #pragma unroll
            for (int r = 0; r < 4; ++r)
                pk[r] = f2bf((acc[m][n][r] + bvv) * scale);
            if (sel == 2) {
                size_t idx = ((size_t)(rr0 >> 11) * 1024 + cc) * 2048 + (rr0 & 2047);
                *(u16x4*)&Vt[idx] = pk;
            } else {
                unsigned short* out = (sel == 0) ? Qo : Ko;
                #pragma unroll
                for (int r = 0; r < 4; ++r)
                    out[(size_t)(rr0 + r) * 1024 + cc] = pk[r];
            }
        }
    }
}

// ---------------- proj GEMM: C[M,N] = A[M,K]*B[N,K]^T + bias (f32 out) ----------------
__global__ void gemm_proj(const unsigned short* __restrict__ A,
                          const unsigned short* __restrict__ B,
                          const float* __restrict__ bias,
                          float* __restrict__ Cout,
                          int M, int N, int K) {
    __shared__ __align__(16) unsigned short As[128 * 32];
    __shared__ __align__(16) unsigned short Bs[128 * 32];
    const int tid  = threadIdx.x;
    const int wid  = tid >> 6;
    const int lane = tid & 63;
    const int lg = lane >> 4, lr = lane & 15;
    const int wr = wid >> 1, wc = wid & 1;
    const int n0 = blockIdx.x * 128;
    const int m0 = blockIdx.y * 128;

    f32x4 acc[4][4] = {};

    for (int kt = 0; kt < K; kt += 32) {
        #pragma unroll
        for (int r = 0; r < 2; ++r) {
            int cb = r * 4 + wid;
            int chunk = cb * 64 + lane;
            int row = chunk >> 2;
            int col = (chunk & 3) * 8;
            async_load16(&A[(size_t)(m0 + row) * K + kt + col], (char*)As + cb * 1024);
            async_load16(&B[(size_t)(n0 + row) * K + kt + col], (char*)Bs + cb * 1024);
        }
        __syncthreads();
        short8 af[4], bfr[4];
        #pragma unroll
        for (int m = 0; m < 4; ++m)
            af[m] = *(const short8*)&As[(wr * 64 + m * 16 + lr) * 32 + lg * 8];
        #pragma unroll
        for (int n = 0; n < 4; ++n)
            bfr[n] = *(const short8*)&Bs[(wc * 64 + n * 16 + lr) * 32 + lg * 8];
        #pragma unroll
        for (int m = 0; m < 4; ++m)
            #pragma unroll
            for (int n = 0; n < 4; ++n)
                acc[m][n] = __builtin_amdgcn_mfma_f32_16x16x32_bf16(af[m], bfr[n], acc[m][n], 0, 0, 0);
        __syncthreads();
    }

    #pragma unroll
    for (int n = 0; n < 4; ++n) {
        int cc = n0 + wc * 64 + n * 16 + lr;
        float bvv = bias[cc];
        #pragma unroll
        for (int m = 0; m < 4; ++m) {
            int rr0 = m0 + wr * 64 + m * 16 + lg * 4;
            #pragma unroll
            for (int r = 0; r < 4; ++r)
                Cout[(size_t)(rr0 + r) * N + cc] = acc[m][n][r] + bvv;
        }
    }
}

// ---------------- flash attention (causal), 32x32 MFMA, BARRIER-FREE ----------------
// One wave per 32-row q-group (grid 4096 = 64 bh x 64 qg). K AND V fragments read
// directly from global (L2-resident, XCD-pinned): no LDS, no __syncthreads, no
// vmcnt(0) convoy -- each wave free-runs its own dependency chain, and the CU
// refills wave slots as short jobs finish (LJF order). Softmax lane-local (exp2),
// defer-rescale THR=8, in-register P redistribution via permlane32_swap.
__global__ __launch_bounds__(64, 1) void attn_fwd13(const unsigned short* __restrict__ Q,
                                                    const unsigned short* __restrict__ Kg,
                                                    const unsigned short* __restrict__ Vt,
                                                    unsigned short* __restrict__ Y) {
    const int bid = blockIdx.x;            // 0..4095
    const int xcd = bid & 7;
    const int s   = bid >> 3;              // 0..511
    const int qg  = 63 - (s >> 3);         // 63..0 (longest-job-first)
    const int bh  = (s & 7) * 8 + xcd;     // 0..63, pinned to this XCD
    const int h   = bh & 15;
    const int b   = bh >> 4;

    const int lane = threadIdx.x;
    const int ql = lane & 31, hi = lane >> 5;

    const size_t rowbase = ((size_t)b * T_SEQ) * C_EMB + (size_t)h * 64;   // Q,K,Y
    const size_t vtbase  = ((size_t)b * 1024 + (size_t)h * 64) * T_SEQ;    // Vt [d][t]

    const int qw0 = qg * 32;
    const int ntiles = qg / 2 + 1;         // K range [0, 32qg+32) in 64-tiles

    // Q B-frags: lane holds Q[qw0+ql][ds*16 + hi*8 .. +8)  (4 d-steps)
    short8 qf[4];
    #pragma unroll
    for (int ds = 0; ds < 4; ++ds)
        qf[ds] = *(const short8*)&Q[rowbase + (size_t)(qw0 + ql) * C_EMB + ds * 16 + hi * 8];

    f32x16 o0 = {}, o1 = {};
    float mrun = -1e30f, lsum = 0.0f;

    #pragma unroll 1
    for (int t = 0; t < ntiles; ++t) {
        const int kv0 = t * 64;

        // K A-frags direct from global: row k = kv0 + (ql | +32), d = ds*16+hi*8
        short8 kf0[4], kf1[4];
        #pragma unroll
        for (int ds = 0; ds < 4; ++ds) {
            kf0[ds] = *(const short8*)&Kg[rowbase + (size_t)(kv0 + ql) * C_EMB + ds * 16 + hi * 8];
            kf1[ds] = *(const short8*)&Kg[rowbase + (size_t)(kv0 + 32 + ql) * C_EMB + ds * 16 + hi * 8];
        }
        // V B-frags direct from global (col d = dblk*32+ql, rows k = ks*16+hi*8+j)
        short8 vf0[4], vf1[4];
        #pragma unroll
        for (int ks = 0; ks < 4; ++ks) {
            vf0[ks] = *(const short8*)&Vt[vtbase + (size_t)ql * T_SEQ + kv0 + ks * 16 + hi * 8];
            vf1[ks] = *(const short8*)&Vt[vtbase + (size_t)(32 + ql) * T_SEQ + kv0 + ks * 16 + hi * 8];
        }

        // ---- S^T = K * Q^T ----
        f32x16 sa0 = {}, sa1 = {};
        __builtin_amdgcn_s_setprio(1);
        #pragma unroll
        for (int ds = 0; ds < 4; ++ds) {
            sa0 = __builtin_amdgcn_mfma_f32_32x32x16_bf16(kf0[ds], qf[ds], sa0, 0, 0, 0);
            sa1 = __builtin_amdgcn_mfma_f32_32x32x16_bf16(kf1[ds], qf[ds], sa1, 0, 0, 0);
        }
        __builtin_amdgcn_s_setprio(0);

        // ---- causal mask (only last tile; C rows: k_local=(r&3)+8*(r>>2)+4*hi) ----
        if (t == ntiles - 1) {
            const int qi = qw0 + ql;
            #pragma unroll
            for (int r = 0; r < 16; ++r) {
                int kl = (r & 3) + 8 * (r >> 2) + 4 * hi;
                if (kv0 + kl > qi)      sa0[r] = -1e30f;
                if (kv0 + 32 + kl > qi) sa1[r] = -1e30f;
            }
        }

        // ---- lane-local online softmax (lane owns q = qw0+ql), exp2 domain ----
        float mx[8];
        #pragma unroll
        for (int r = 0; r < 8; ++r)
            mx[r] = fmaxf(fmaxf(sa0[r], sa0[r + 8]), fmaxf(sa1[r], sa1[r + 8]));
        mx[0] = fmaxf(mx[0], mx[4]); mx[1] = fmaxf(mx[1], mx[5]);
        mx[2] = fmaxf(mx[2], mx[6]); mx[3] = fmaxf(mx[3], mx[7]);
        float tmax = fmaxf(fmaxf(mx[0], mx[1]), fmaxf(mx[2], mx[3]));
        tmax = plswap_max(tmax);
        // defer-rescale (THR=8)
        if (!__all(tmax <= mrun + 8.0f)) {
            float mn  = fmaxf(mrun, tmax);
            float scl = exp2f(mrun - mn);
            mrun = mn;
            lsum *= scl;
            #pragma unroll
            for (int gg = 0; gg < 4; ++gg)
                #pragma unroll
                for (int r2 = 0; r2 < 4; ++r2) {
                    float sc = __shfl(scl, gg * 8 + 4 * hi + r2);
                    o0[gg * 4 + r2] *= sc;
                    o1[gg * 4 + r2] *= sc;
                }
        }
        #pragma unroll
        for (int r = 0; r < 16; ++r) {
            sa0[r] = exp2f(sa0[r] - mrun);
            sa1[r] = exp2f(sa1[r] - mrun);
        }
        float sm[8];
        #pragma unroll
        for (int r = 0; r < 8; ++r)
            sm[r] = (sa0[r] + sa0[r + 8]) + (sa1[r] + sa1[r + 8]);
        lsum += ((sm[0] + sm[1]) + (sm[2] + sm[3])) + ((sm[4] + sm[5]) + (sm[6] + sm[7]));

        // ---- P -> bf16 packed words ----
        unsigned pw0[8], pw1[8];
        #pragma unroll
        for (int gg = 0; gg < 4; ++gg)
            #pragma unroll
            for (int hh = 0; hh < 2; ++hh) {
                asm("v_cvt_pk_bf16_f32 %0, %1, %2"
                    : "=v"(pw0[gg * 2 + hh]) : "v"(sa0[4 * gg + 2 * hh]), "v"(sa0[4 * gg + 2 * hh + 1]));
                asm("v_cvt_pk_bf16_f32 %0, %1, %2"
                    : "=v"(pw1[gg * 2 + hh]) : "v"(sa1[4 * gg + 2 * hh]), "v"(sa1[4 * gg + 2 * hh + 1]));
            }

        // ---- in-register P redistribution via permlane32_swap ----
        short8 pf[4];
        #pragma unroll
        for (int ks = 0; ks < 4; ++ks) {
            const int g0 = (2 * ks) & 3, g1 = (2 * ks + 1) & 3;
            unsigned p0, q0c, p1, q1c;
            if (ks < 2) { p0 = pw0[g0 * 2]; p1 = pw0[g0 * 2 + 1];
                          q0c = pw0[g1 * 2]; q1c = pw0[g1 * 2 + 1]; }
            else        { p0 = pw1[g0 * 2]; p1 = pw1[g0 * 2 + 1];
                          q0c = pw1[g1 * 2]; q1c = pw1[g1 * 2 + 1]; }
            plswap_u(p0, q0c);
            plswap_u(p1, q1c);
            union { unsigned u[4]; short8 v; } uu;
            uu.u[0] = p0;
            uu.u[1] = p1;
            uu.u[2] = q0c;
            uu.u[3] = q1c;
            pf[ks] = uu.v;
        }

        // ---- PV ----
        __builtin_amdgcn_s_setprio(1);
        #pragma unroll
        for (int ks = 0; ks < 4; ++ks) {
            o0 = __builtin_amdgcn_mfma_f32_32x32x16_bf16(pf[ks], vf0[ks], o0, 0, 0, 0);
            o1 = __builtin_amdgcn_mfma_f32_32x32x16_bf16(pf[ks], vf1[ks], o1, 0, 0, 0);
        }
        __builtin_amdgcn_s_setprio(0);
    }

    // ---- epilogue ----
    lsum = plswap_sum(lsum);
    float linv = 1.0f / lsum;
    #pragma unroll
    for (int gg = 0; gg < 4; ++gg)
        #pragma unroll
        for (int r2 = 0; r2 < 4; ++r2) {
            int row = gg * 8 + 4 * hi + r2;
            float li = __shfl(linv, row);
            size_t ybase = rowbase + (size_t)(qw0 + row) * C_EMB;
            Y[ybase + ql]      = f2bf(o0[gg * 4 + r2] * li);
            Y[ybase + 32 + ql] = f2bf(o1[gg * 4 + r2] * li);
        }
}

// ---------------- launcher ----------------
extern "C" void kernel_launch(void* const* d_in, const int* in_sizes, int n_in,
                              void* d_out, int out_size, void* d_ws, size_t ws_size,
                              hipStream_t stream) {
    const float* x  = (const float*)d_in[0];
    const float* Wk = (const float*)d_in[1];
    const float* bk = (const float*)d_in[2];
    const float* Wq = (const float*)d_in[3];
    const float* bq = (const float*)d_in[4];
    const float* Wv = (const float*)d_in[5];
    const float* bv = (const float*)d_in[6];
    const float* Wp = (const float*)d_in[7];
    const float* bp = (const float*)d_in[8];

    const size_t SX = (size_t)8192 * 1024;
    const size_t SW = (size_t)1024 * 1024;

    char* ws = (char*)d_ws;
    unsigned short* xb   = (unsigned short*)ws; ws += SX * 2;
    unsigned short* Wqkv = (unsigned short*)ws; ws += 3 * SW * 2;  // [Wq;Wk;Wv] rows
    unsigned short* Wpb  = (unsigned short*)ws; ws += SW * 2;
    unsigned short* qb   = (unsigned short*)ws; ws += SX * 2;
    unsigned short* kb   = (unsigned short*)ws; ws += SX * 2;
    unsigned short* vtb  = (unsigned short*)ws; ws += SX * 2;  // V^T per head [b][h][d][t]
    unsigned short* yb   = (unsigned short*)ws; ws += SX * 2;

    cvt_all<<<dim3(12288), 256, 0, stream>>>(x, Wq, Wk, Wv, Wp, xb, Wqkv, Wpb);

    gemm_qkv<<<dim3(24, 64), 256, 0, stream>>>(xb, Wqkv, bq, bk, bv, qb, kb, vtb);

    attn_fwd13<<<dim3(4096), 64, 0, stream>>>(qb, kb, vtb, yb);

    gemm_proj<<<dim3(8, 64), 256, 0, stream>>>(yb, Wpb, bp, (float*)d_out, 8192, 1024, 1024);
}

// Round 14
// 193.602 us; speedup vs baseline: 1.2274x; 1.2274x over previous
//
#include <hip/hip_runtime.h>

typedef __attribute__((ext_vector_type(8))) short short8;
typedef __attribute__((ext_vector_type(4))) float f32x4;
typedef __attribute__((ext_vector_type(16))) float f32x16;
typedef __attribute__((ext_vector_type(4))) unsigned short u16x4;
typedef __attribute__((ext_vector_type(4))) float float4v;

#define AS1 __attribute__((address_space(1)))
#define AS3 __attribute__((address_space(3)))

#define T_SEQ 2048
#define C_EMB 1024
#define NHEAD 16
#define NB    4
#define SCL_Q 0.18033688f   // 0.125 * log2(e)

__device__ __forceinline__ unsigned short f2bf(float f) {
    union { float f; unsigned u; } cv; cv.f = f;
    unsigned u = cv.u;
    unsigned r = (u + 0x7FFFu + ((u >> 16) & 1u)) >> 16;
    return (unsigned short)r;
}

__device__ __forceinline__ void async_load16(const void* g, void* l) {
    __builtin_amdgcn_global_load_lds((const AS1 unsigned*)g, (AS3 unsigned*)l, 16, 0, 0);
}

// permlane32_swap builtin (R12-proven): r[0] = {a.lo-lanes, b.lo-lanes}, r[1] = {a.hi, b.hi}
__device__ __forceinline__ void plswap_u(unsigned &a, unsigned &b) {
    auto r = __builtin_amdgcn_permlane32_swap(a, b, false, false);
    a = r[0]; b = r[1];
}
__device__ __forceinline__ float plswap_max(float t) {
    union { float f; unsigned u; } c; c.f = t;
    auto r = __builtin_amdgcn_permlane32_swap(c.u, c.u, false, false);
    union { unsigned u; float f; } x0, x1; x0.u = r[0]; x1.u = r[1];
    return fmaxf(x0.f, x1.f);
}
__device__ __forceinline__ float plswap_sum(float t) {
    union { float f; unsigned u; } c; c.f = t;
    auto r = __builtin_amdgcn_permlane32_swap(c.u, c.u, false, false);
    union { unsigned u; float f; } x0, x1; x0.u = r[0]; x1.u = r[1];
    return x0.f + x1.f;
}

// ---------------- fused f32 -> bf16 convert (x + 4 weights, one launch; R13-proven) ----------------
__global__ void cvt_all(const float* __restrict__ x,
                        const float* __restrict__ wq, const float* __restrict__ wk,
                        const float* __restrict__ wv, const float* __restrict__ wp,
                        unsigned short* __restrict__ xb,
                        unsigned short* __restrict__ wqkv,
                        unsigned short* __restrict__ wpb) {
    const int blk = blockIdx.x;
    const float* src; unsigned short* dst; int idx;
    if (blk < 8192) {                       // x: 8M elems = 2M float4 = 8192 blocks
        src = x; dst = xb; idx = blk * 256 + threadIdx.x;
    } else {                                 // weights: 1024 blocks each
        int wsel = (blk - 8192) >> 10;
        idx = ((blk - 8192) & 1023) * 256 + threadIdx.x;
        src = (wsel == 0) ? wq : (wsel == 1) ? wk : (wsel == 2) ? wv : wp;
        dst = (wsel == 3) ? wpb : wqkv + (size_t)wsel * 1048576;
    }
    float4v v = ((const float4v*)src)[idx];
    u16x4 o;
    o[0] = f2bf(v[0]); o[1] = f2bf(v[1]); o[2] = f2bf(v[2]); o[3] = f2bf(v[3]);
    ((u16x4*)dst)[idx] = o;
}

// ---------------- fused QKV GEMM: [8192,1024] x [3072,1024]^T ----------------
__global__ void gemm_qkv(const unsigned short* __restrict__ A,
                         const unsigned short* __restrict__ W,
                         const float* __restrict__ bq,
                         const float* __restrict__ bk,
                         const float* __restrict__ bv,
                         unsigned short* __restrict__ Qo,
                         unsigned short* __restrict__ Ko,
                         unsigned short* __restrict__ Vt) {
    __shared__ __align__(16) unsigned short As[128 * 32];
    __shared__ __align__(16) unsigned short Bs[128 * 32];
    const int tid  = threadIdx.x;
    const int wid  = tid >> 6;
    const int lane = tid & 63;
    const int lg = lane >> 4, lr = lane & 15;
    const int wr = wid >> 1, wc = wid & 1;
    const int n0 = blockIdx.x * 128;
    const int m0 = blockIdx.y * 128;
    const int K = 1024;

    f32x4 acc[4][4] = {};

    for (int kt = 0; kt < K; kt += 32) {
        #pragma unroll
        for (int r = 0; r < 2; ++r) {
            int cb = r * 4 + wid;
            int chunk = cb * 64 + lane;
            int row = chunk >> 2;
            int col = (chunk & 3) * 8;
            async_load16(&A[(size_t)(m0 + row) * K + kt + col], (char*)As + cb * 1024);
            async_load16(&W[(size_t)(n0 + row) * K + kt + col], (char*)Bs + cb * 1024);
        }
        __syncthreads();
        short8 af[4], bfr[4];
        #pragma unroll
        for (int m = 0; m < 4; ++m)
            af[m] = *(const short8*)&As[(wr * 64 + m * 16 + lr) * 32 + lg * 8];
        #pragma unroll
        for (int n = 0; n < 4; ++n)
            bfr[n] = *(const short8*)&Bs[(wc * 64 + n * 16 + lr) * 32 + lg * 8];
        #pragma unroll
        for (int m = 0; m < 4; ++m)
            #pragma unroll
            for (int n = 0; n < 4; ++n)
                acc[m][n] = __builtin_amdgcn_mfma_f32_16x16x32_bf16(af[m], bfr[n], acc[m][n], 0, 0, 0);
        __syncthreads();
    }

    const int sel = n0 >> 10;                       // 0=Q 1=K 2=V (block-uniform)
    const int nl0 = n0 & 1023;
    const float* bias = (sel == 0) ? bq : (sel == 1) ? bk : bv;
    const float scale = (sel == 0) ? SCL_Q : 1.0f;

    #pragma unroll
    for (int n = 0; n < 4; ++n) {
        int cc = nl0 + wc * 64 + n * 16 + lr;
        float bvv = bias[cc];
        #pragma unroll
        for (int m = 0; m < 4; ++m) {
            int rr0 = m0 + wr * 64 + m * 16 + lg * 4;
            u16x4 pk;
            #pragma unroll
            for (int r = 0; r < 4; ++r)
                pk[r] = f2bf((acc[m][n][r] + bvv) * scale);
            if (sel == 2) {
                size_t idx = ((size_t)(rr0 >> 11) * 1024 + cc) * 2048 + (rr0 & 2047);
                *(u16x4*)&Vt[idx] = pk;
            } else {
                unsigned short* out = (sel == 0) ? Qo : Ko;
                #pragma unroll
                for (int r = 0; r < 4; ++r)
                    out[(size_t)(rr0 + r) * 1024 + cc] = pk[r];
            }
        }
    }
}

// ---------------- proj GEMM: C[M,N] = A[M,K]*B[N,K]^T + bias (f32 out) ----------------
__global__ void gemm_proj(const unsigned short* __restrict__ A,
                          const unsigned short* __restrict__ B,
                          const float* __restrict__ bias,
                          float* __restrict__ Cout,
                          int M, int N, int K) {
    __shared__ __align__(16) unsigned short As[128 * 32];
    __shared__ __align__(16) unsigned short Bs[128 * 32];
    const int tid  = threadIdx.x;
    const int wid  = tid >> 6;
    const int lane = tid & 63;
    const int lg = lane >> 4, lr = lane & 15;
    const int wr = wid >> 1, wc = wid & 1;
    const int n0 = blockIdx.x * 128;
    const int m0 = blockIdx.y * 128;

    f32x4 acc[4][4] = {};

    for (int kt = 0; kt < K; kt += 32) {
        #pragma unroll
        for (int r = 0; r < 2; ++r) {
            int cb = r * 4 + wid;
            int chunk = cb * 64 + lane;
            int row = chunk >> 2;
            int col = (chunk & 3) * 8;
            async_load16(&A[(size_t)(m0 + row) * K + kt + col], (char*)As + cb * 1024);
            async_load16(&B[(size_t)(n0 + row) * K + kt + col], (char*)Bs + cb * 1024);
        }
        __syncthreads();
        short8 af[4], bfr[4];
        #pragma unroll
        for (int m = 0; m < 4; ++m)
            af[m] = *(const short8*)&As[(wr * 64 + m * 16 + lr) * 32 + lg * 8];
        #pragma unroll
        for (int n = 0; n < 4; ++n)
            bfr[n] = *(const short8*)&Bs[(wc * 64 + n * 16 + lr) * 32 + lg * 8];
        #pragma unroll
        for (int m = 0; m < 4; ++m)
            #pragma unroll
            for (int n = 0; n < 4; ++n)
                acc[m][n] = __builtin_amdgcn_mfma_f32_16x16x32_bf16(af[m], bfr[n], acc[m][n], 0, 0, 0);
        __syncthreads();
    }

    #pragma unroll
    for (int n = 0; n < 4; ++n) {
        int cc = n0 + wc * 64 + n * 16 + lr;
        float bvv = bias[cc];
        #pragma unroll
        for (int m = 0; m < 4; ++m) {
            int rr0 = m0 + wr * 64 + m * 16 + lg * 4;
            #pragma unroll
            for (int r = 0; r < 4; ++r)
                Cout[(size_t)(rr0 + r) * N + cc] = acc[m][n][r] + bvv;
        }
    }
}

// ---------------- flash attention (causal), 32x32 MFMA, 4-wave blocks (R7 geometry) ----------------
// Best-measured attn geometry (R7: 90us): 4 waves x 32 q-rows = 128 q/block, grid 1024,
// K dbuf in swizzled LDS shared by all 4 waves, V^T reg prefetch, XCD-pinned bh, LJF.
// Plus R12-proven permlane32_swap builtins for all cross-half exchanges (no ds_bpermute
// in the tmax/lsum/P-redistribution chain).
__global__ __launch_bounds__(256, 2) void attn_fwd14(const unsigned short* __restrict__ Q,
                                                     const unsigned short* __restrict__ Kg,
                                                     const unsigned short* __restrict__ Vt,
                                                     unsigned short* __restrict__ Y) {
    __shared__ __align__(16) unsigned short Ks[2][64 * 64];   // 2 x 8KB, swizzled

    const int bid = blockIdx.x;            // 0..1023
    const int xcd = bid & 7;
    const int s   = bid >> 3;              // 0..127
    const int grp = 15 - (s >> 3);         // 15..0 (longest-job-first)
    const int bh  = (s & 7) * 8 + xcd;     // 0..63, pinned to this XCD
    const int h   = bh & 15;
    const int b   = bh >> 4;

    const int tid  = threadIdx.x;
    const int w    = tid >> 6;
    const int lane = tid & 63;
    const int ql = lane & 31, hi = lane >> 5;

    const size_t rowbase = ((size_t)b * T_SEQ) * C_EMB + (size_t)h * 64;   // Q,K,Y
    const size_t vtbase  = ((size_t)b * 1024 + (size_t)h * 64) * T_SEQ;    // Vt [d][t]

    const int srow = lane >> 3;
    const int scol = ((lane & 7) ^ srow) * 8;

    const int q0  = grp * 128;
    const int qw0 = q0 + w * 32;
    const int ntiles = 2 * grp + 2;

    // Q B-frags: lane holds Q[qw0+ql][ds*16 + hi*8 .. +8)  (4 d-steps)
    short8 qf[4];
    #pragma unroll
    for (int ds = 0; ds < 4; ++ds)
        qf[ds] = *(const short8*)&Q[rowbase + (size_t)(qw0 + ql) * C_EMB + ds * 16 + hi * 8];

    f32x16 o0 = {}, o1 = {};
    float mrun = -1e30f, lsum = 0.0f;

    // prologue: stage K tile 0 -> buf 0 (8 chunks of 1KB; 2 per wave)
    #pragma unroll
    for (int i = 0; i < 2; ++i) {
        int cb = w * 2 + i;
        async_load16(&Kg[rowbase + (size_t)(cb * 8 + srow) * C_EMB + scol],
                     (char*)Ks[0] + cb * 1024);
    }

    #pragma unroll 1
    for (int t = 0; t < ntiles; ++t) {
        const int kv0 = t * 64;
        const int cur = t & 1, nxt = cur ^ 1;
        __syncthreads();   // K[t] ready; buf[nxt] free

        const bool active = (kv0 <= qw0 + 31);

        // V prefetch to regs (B-frags: col d = dblk*32+ql, rows k = ks*16+hi*8+j)
        short8 vf0[4], vf1[4];
        if (active) {
            #pragma unroll
            for (int ks = 0; ks < 4; ++ks) {
                vf0[ks] = *(const short8*)&Vt[vtbase + (size_t)ql * T_SEQ + kv0 + ks * 16 + hi * 8];
                vf1[ks] = *(const short8*)&Vt[vtbase + (size_t)(32 + ql) * T_SEQ + kv0 + ks * 16 + hi * 8];
            }
        }
        // stage next K tile
        if (t + 1 < ntiles) {
            #pragma unroll
            for (int i = 0; i < 2; ++i) {
                int cb = w * 2 + i;
                async_load16(&Kg[rowbase + (size_t)(kv0 + 64 + cb * 8 + srow) * C_EMB + scol],
                             (char*)Ks[nxt] + cb * 1024);
            }
        }
        if (!active) continue;   // fully-masked tile: barrier+stage only

        // ---- S^T = K * Q^T : A = K[32k x 16d] (row=ql), B = Q^T (col=ql) ----
        f32x16 sa0 = {}, sa1 = {};
        __builtin_amdgcn_s_setprio(1);
        #pragma unroll
        for (int ds = 0; ds < 4; ++ds) {
            short8 a0 = *(const short8*)((const char*)Ks[cur] + (ql) * 128 +
                                         ((ds * 32 + hi * 16) ^ ((ql & 7) << 4)));
            short8 a1 = *(const short8*)((const char*)Ks[cur] + (32 + ql) * 128 +
                                         ((ds * 32 + hi * 16) ^ ((ql & 7) << 4)));
            sa0 = __builtin_amdgcn_mfma_f32_32x32x16_bf16(a0, qf[ds], sa0, 0, 0, 0);
            sa1 = __builtin_amdgcn_mfma_f32_32x32x16_bf16(a1, qf[ds], sa1, 0, 0, 0);
        }
        __builtin_amdgcn_s_setprio(0);

        // ---- causal mask (C rows: k_local = (r&3)+8*(r>>2)+4*hi) ----
        if (kv0 + 63 > qw0) {
            const int qi = qw0 + ql;
            #pragma unroll
            for (int r = 0; r < 16; ++r) {
                int kl = (r & 3) + 8 * (r >> 2) + 4 * hi;
                if (kv0 + kl > qi)      sa0[r] = -1e30f;
                if (kv0 + 32 + kl > qi) sa1[r] = -1e30f;
            }
        }

        // ---- lane-local online softmax (lane owns q = qw0+ql), exp2 domain ----
        float mx[8];
        #pragma unroll
        for (int r = 0; r < 8; ++r)
            mx[r] = fmaxf(fmaxf(sa0[r], sa0[r + 8]), fmaxf(sa1[r], sa1[r + 8]));
        mx[0] = fmaxf(mx[0], mx[4]); mx[1] = fmaxf(mx[1], mx[5]);
        mx[2] = fmaxf(mx[2], mx[6]); mx[3] = fmaxf(mx[3], mx[7]);
        float tmax = fmaxf(fmaxf(mx[0], mx[1]), fmaxf(mx[2], mx[3]));
        tmax = plswap_max(tmax);
        // defer-rescale (THR=8)
        if (!__all(tmax <= mrun + 8.0f)) {
            float mn  = fmaxf(mrun, tmax);
            float scl = exp2f(mrun - mn);
            mrun = mn;
            lsum *= scl;
            #pragma unroll
            for (int gg = 0; gg < 4; ++gg)
                #pragma unroll
                for (int r2 = 0; r2 < 4; ++r2) {
                    float sc = __shfl(scl, gg * 8 + 4 * hi + r2);
                    o0[gg * 4 + r2] *= sc;
                    o1[gg * 4 + r2] *= sc;
                }
        }
        #pragma unroll
        for (int r = 0; r < 16; ++r) {
            sa0[r] = exp2f(sa0[r] - mrun);
            sa1[r] = exp2f(sa1[r] - mrun);
        }
        float sm[8];
        #pragma unroll
        for (int r = 0; r < 8; ++r)
            sm[r] = (sa0[r] + sa0[r + 8]) + (sa1[r] + sa1[r + 8]);
        lsum += ((sm[0] + sm[1]) + (sm[2] + sm[3])) + ((sm[4] + sm[5]) + (sm[6] + sm[7]));

        // ---- P -> bf16 packed words: pw[g*2+h] = pack(p[4g+2h], p[4g+2h+1]) ----
        unsigned pw0[8], pw1[8];
        #pragma unroll
        for (int gg = 0; gg < 4; ++gg)
            #pragma unroll
            for (int hh = 0; hh < 2; ++hh) {
                asm("v_cvt_pk_bf16_f32 %0, %1, %2"
                    : "=v"(pw0[gg * 2 + hh]) : "v"(sa0[4 * gg + 2 * hh]), "v"(sa0[4 * gg + 2 * hh + 1]));
                asm("v_cvt_pk_bf16_f32 %0, %1, %2"
                    : "=v"(pw1[gg * 2 + hh]) : "v"(sa1[4 * gg + 2 * hh]), "v"(sa1[4 * gg + 2 * hh + 1]));
            }

        // ---- in-register P redistribution via permlane32_swap builtin (R12-proven):
        //      r = swap(g0h, g1h) -> r[0] = {g0h.lo, g1h.lo} (word0/1),
        //                            r[1] = {g0h.hi, g1h.hi} (word2/3) ----
        short8 pf[4];
        #pragma unroll
        for (int ks = 0; ks < 4; ++ks) {
            const int g0 = (2 * ks) & 3, g1 = (2 * ks + 1) & 3;
            unsigned p0, q0c, p1, q1c;
            if (ks < 2) { p0 = pw0[g0 * 2]; p1 = pw0[g0 * 2 + 1];
                          q0c = pw0[g1 * 2]; q1c = pw0[g1 * 2 + 1]; }
            else        { p0 = pw1[g0 * 2]; p1 = pw1[g0 * 2 + 1];
                          q0c = pw1[g1 * 2]; q1c = pw1[g1 * 2 + 1]; }
            plswap_u(p0, q0c);
            plswap_u(p1, q1c);
            union { unsigned u[4]; short8 v; } uu;
            uu.u[0] = p0;
            uu.u[1] = p1;
            uu.u[2] = q0c;
            uu.u[3] = q1c;
            pf[ks] = uu.v;
        }

        // ---- PV: O[32q x 32d] x 2 d-blocks ----
        __builtin_amdgcn_s_setprio(1);
        #pragma unroll
        for (int ks = 0; ks < 4; ++ks) {
            o0 = __builtin_amdgcn_mfma_f32_32x32x16_bf16(pf[ks], vf0[ks], o0, 0, 0, 0);
            o1 = __builtin_amdgcn_mfma_f32_32x32x16_bf16(pf[ks], vf1[ks], o1, 0, 0, 0);
        }
        __builtin_amdgcn_s_setprio(0);
    }

    // ---- epilogue: lsum across halves, then normalize + store ----
    lsum = plswap_sum(lsum);
    float linv = 1.0f / lsum;
    #pragma unroll
    for (int gg = 0; gg < 4; ++gg)
        #pragma unroll
        for (int r2 = 0; r2 < 4; ++r2) {
            int row = gg * 8 + 4 * hi + r2;
            float li = __shfl(linv, row);
            size_t ybase = rowbase + (size_t)(qw0 + row) * C_EMB;
            Y[ybase + ql]      = f2bf(o0[gg * 4 + r2] * li);
            Y[ybase + 32 + ql] = f2bf(o1[gg * 4 + r2] * li);
        }
}

// ---------------- launcher ----------------
extern "C" void kernel_launch(void* const* d_in, const int* in_sizes, int n_in,
                              void* d_out, int out_size, void* d_ws, size_t ws_size,
                              hipStream_t stream) {
    const float* x  = (const float*)d_in[0];
    const float* Wk = (const float*)d_in[1];
    const float* bk = (const float*)d_in[2];
    const float* Wq = (const float*)d_in[3];
    const float* bq = (const float*)d_in[4];
    const float* Wv = (const float*)d_in[5];
    const float* bv = (const float*)d_in[6];
    const float* Wp = (const float*)d_in[7];
    const float* bp = (const float*)d_in[8];

    const size_t SX = (size_t)8192 * 1024;
    const size_t SW = (size_t)1024 * 1024;

    char* ws = (char*)d_ws;
    unsigned short* xb   = (unsigned short*)ws; ws += SX * 2;
    unsigned short* Wqkv = (unsigned short*)ws; ws += 3 * SW * 2;  // [Wq;Wk;Wv] rows
    unsigned short* Wpb  = (unsigned short*)ws; ws += SW * 2;
    unsigned short* qb   = (unsigned short*)ws; ws += SX * 2;
    unsigned short* kb   = (unsigned short*)ws; ws += SX * 2;
    unsigned short* vtb  = (unsigned short*)ws; ws += SX * 2;  // V^T per head [b][h][d][t]
    unsigned short* yb   = (unsigned short*)ws; ws += SX * 2;

    cvt_all<<<dim3(12288), 256, 0, stream>>>(x, Wq, Wk, Wv, Wp, xb, Wqkv, Wpb);

    gemm_qkv<<<dim3(24, 64), 256, 0, stream>>>(xb, Wqkv, bq, bk, bv, qb, kb, vtb);

    attn_fwd14<<<dim3(1024), 256, 0, stream>>>(qb, kb, vtb, yb);

    gemm_proj<<<dim3(8, 64), 256, 0, stream>>>(yb, Wpb, bp, (float*)d_out, 8192, 1024, 1024);
}